// Round 1
// baseline (657.380 us; speedup 1.0000x reference)
//
#include <hip/hip_runtime.h>
#include <hip/hip_bf16.h>

// Problem dims (fixed by the reference): B=64, Te=1024, De=Dd=H=1024.
#define B_  64
#define TE  1024
#define DE  1024
#define HH  1024
#define MM  (B_ * TE)      // 65536 rows of the score GEMM

typedef __bf16 bf16x8 __attribute__((ext_vector_type(8)));
typedef __bf16 bf16x4 __attribute__((ext_vector_type(4)));
typedef float  f32x4  __attribute__((ext_vector_type(4)));

// ---------------------------------------------------------------- zero
__global__ void zero_kernel(float* __restrict__ a, float* __restrict__ b, int n) {
    int i = blockIdx.x * blockDim.x + threadIdx.x;
    if (i < n) { a[i] = 0.0f; b[i] = 0.0f; }
}

// ---------------------------------------------------------------- fp32 -> bf16
__global__ void cvt_kernel(const float* __restrict__ in, __bf16* __restrict__ out, long n4) {
    long i = (long)blockIdx.x * blockDim.x + threadIdx.x;
    long stride = (long)gridDim.x * blockDim.x;
    const float4* in4 = (const float4*)in;
    bf16x4* out4 = (bf16x4*)out;
    for (long j = i; j < n4; j += stride) {
        float4 v = in4[j];
        bf16x4 o;
        o[0] = (__bf16)v.x; o[1] = (__bf16)v.y; o[2] = (__bf16)v.z; o[3] = (__bf16)v.w;
        out4[j] = o;
    }
}

// ---------------------------------------------------------------- Wa[b,h] = dec[b]·Wa_w[h] + Wa_b[h]
// grid (64, 16), block 256. Wave computes one h at a time via lane-strided dot.
__global__ void wa_kernel(const float* __restrict__ dec, const float* __restrict__ Wa_w,
                          const float* __restrict__ Wa_b, float* __restrict__ WaOut) {
    int b = blockIdx.x, ht = blockIdx.y;
    int wave = threadIdx.x >> 6, lane = threadIdx.x & 63;
    const float* db = dec + b * 1024;
    for (int i = 0; i < 16; i++) {
        int h = ht * 64 + wave * 16 + i;
        const float* wr = Wa_w + (long)h * 1024;
        float a = 0.0f;
        #pragma unroll
        for (int k = 0; k < 16; k++)
            a += db[lane + 64 * k] * wr[lane + 64 * k];
        #pragma unroll
        for (int off = 32; off > 0; off >>= 1)
            a += __shfl_xor(a, off, 64);
        if (lane == 0) WaOut[b * 1024 + h] = a + Wa_b[h];
    }
}

// ---------------------------------------------------------------- fused score GEMM
// C[m, h] = enc_bf16[m,:]·Ua_w_bf16[h,:]  (both row-major [row][K], K=1024)
// score[m] += sum_h Va_w[h]*tanh(C + Wa[b,h] + Ua_b[h])   (Va_b dropped: softmax-invariant)
// 128x128 tile, BK=32, 4 waves in 2x2, each wave 4x4 subtiles of 16x16x32 MFMA.
#define MT 128
#define NT 128
#define KT 32

__global__ __launch_bounds__(256, 2) void score_gemm(
    const __bf16* __restrict__ A,    // [MM][1024] enc bf16
    const __bf16* __restrict__ Bm,   // [1024][1024] Ua_w bf16 (h-major, d contiguous)
    const float* __restrict__ Wa,    // [64][1024]
    const float* __restrict__ Ua_b,  // [1024]
    const float* __restrict__ Va_w,  // [1024]
    float* __restrict__ scores)      // [MM], pre-zeroed, atomic accumulate
{
    __shared__ __bf16 sA[MT * KT];   // 8 KB, [m][k] row-major, NO padding (global_load_lds)
    __shared__ __bf16 sB[NT * KT];   // 8 KB, [n][k] row-major
    __shared__ float sVa[NT];
    __shared__ float sWU[NT];
    __shared__ float sRow[MT];

    const int tid  = threadIdx.x;
    const int wave = tid >> 6;
    const int lane = tid & 63;
    const int quad = lane >> 4;
    const int l16  = lane & 15;
    const int wm   = wave >> 1;      // 0..1 (m half)
    const int wn   = wave & 1;       // 0..1 (n half)

    const int rowBase = blockIdx.x * MT;
    const int n0      = blockIdx.y * NT;
    const int b       = rowBase >> 10;   // Te=1024 rows per batch, MT divides 1024

    if (tid < NT) {
        int h = n0 + tid;
        sVa[tid]  = Va_w[h];
        sWU[tid]  = Wa[b * 1024 + h] + Ua_b[h];
        sRow[tid] = 0.0f;
    }

    f32x4 acc[4][4] = {};

    const int K = 1024;
    const long aBase = (long)rowBase * K;
    const long bBase = (long)n0 * K;

    for (int k0 = 0; k0 < K; k0 += KT) {
        __syncthreads();   // previous iter's ds_reads complete before overwrite
        #pragma unroll
        for (int i = 0; i < 2; i++) {
            int c = i * 256 + tid;           // 16B chunk index; row = c>>2, seg = c&3
            int r = c >> 2, cc = c & 3;
            const __bf16* ga = A + aBase + (long)r * K + k0 + cc * 8;
            __builtin_amdgcn_global_load_lds(
                (const __attribute__((address_space(1))) unsigned int*)ga,
                (__attribute__((address_space(3))) unsigned int*)(sA + c * 8), 16, 0, 0);
            const __bf16* gb = Bm + bBase + (long)r * K + k0 + cc * 8;
            __builtin_amdgcn_global_load_lds(
                (const __attribute__((address_space(1))) unsigned int*)gb,
                (__attribute__((address_space(3))) unsigned int*)(sB + c * 8), 16, 0, 0);
        }
        __syncthreads();   // drains vmcnt: staged data visible

        bf16x8 af[4], bfr[4];
        #pragma unroll
        for (int s = 0; s < 4; s++) {
            af[s]  = *(const bf16x8*)(sA + (wm * 64 + s * 16 + l16) * KT + quad * 8);
            bfr[s] = *(const bf16x8*)(sB + (wn * 64 + s * 16 + l16) * KT + quad * 8);
        }
        #pragma unroll
        for (int s = 0; s < 4; s++)
            #pragma unroll
            for (int t = 0; t < 4; t++)
                acc[s][t] = __builtin_amdgcn_mfma_f32_16x16x32_bf16(af[s], bfr[t], acc[s][t], 0, 0, 0);
    }
    __syncthreads();

    // Epilogue: score contribution = sum over this block's 128 h of Va*tanh(acc + Wa + Ua_b)
    // C/D layout (verified): row = quad*4 + reg, col = l16.
    #pragma unroll
    for (int s = 0; s < 4; s++) {
        float rs0 = 0, rs1 = 0, rs2 = 0, rs3 = 0;
        #pragma unroll
        for (int t = 0; t < 4; t++) {
            int hl = wn * 64 + t * 16 + l16;
            float va = sVa[hl], wu = sWU[hl];
            rs0 += va * tanhf(acc[s][t][0] + wu);
            rs1 += va * tanhf(acc[s][t][1] + wu);
            rs2 += va * tanhf(acc[s][t][2] + wu);
            rs3 += va * tanhf(acc[s][t][3] + wu);
        }
        #pragma unroll
        for (int off = 1; off < 16; off <<= 1) {
            rs0 += __shfl_xor(rs0, off, 64);
            rs1 += __shfl_xor(rs1, off, 64);
            rs2 += __shfl_xor(rs2, off, 64);
            rs3 += __shfl_xor(rs3, off, 64);
        }
        if (l16 == 0) {
            int rl = wm * 64 + s * 16 + quad * 4;
            atomicAdd(&sRow[rl + 0], rs0);
            atomicAdd(&sRow[rl + 1], rs1);
            atomicAdd(&sRow[rl + 2], rs2);
            atomicAdd(&sRow[rl + 3], rs3);
        }
    }
    __syncthreads();
    if (tid < MT) atomicAdd(&scores[rowBase + tid], sRow[tid]);
}

// ---------------------------------------------------------------- softmax over Te, in place
__global__ void softmax_kernel(float* __restrict__ s) {
    __shared__ float red[256];
    int b = blockIdx.x, tid = threadIdx.x;
    float4* row = (float4*)(s + b * 1024);
    float4 v = row[tid];
    float m = fmaxf(fmaxf(v.x, v.y), fmaxf(v.z, v.w));
    red[tid] = m; __syncthreads();
    for (int off = 128; off > 0; off >>= 1) {
        if (tid < off) red[tid] = fmaxf(red[tid], red[tid + off]);
        __syncthreads();
    }
    m = red[0]; __syncthreads();
    v.x = expf(v.x - m); v.y = expf(v.y - m); v.z = expf(v.z - m); v.w = expf(v.w - m);
    red[tid] = v.x + v.y + v.z + v.w; __syncthreads();
    for (int off = 128; off > 0; off >>= 1) {
        if (tid < off) red[tid] += red[tid + off];
        __syncthreads();
    }
    float inv = 1.0f / red[0];
    v.x *= inv; v.y *= inv; v.z *= inv; v.w *= inv;
    row[tid] = v;
}

// ---------------------------------------------------------------- context[b,d] = sum_e w[b,e] enc[b,e,d]
// grid (64, 16): each block covers 64 e's, atomic-accumulates into pre-zeroed out.
__global__ void context_kernel(const float* __restrict__ enc, const float* __restrict__ w,
                               float* __restrict__ out) {
    int b = blockIdx.x, ec = blockIdx.y, tid = threadIdx.x;
    const float4* enc4 = (const float4*)(enc + ((long)b * 1024 + ec * 64) * 1024);
    const float* wrow = w + b * 1024 + ec * 64;
    float4 acc = {0, 0, 0, 0};
    for (int e = 0; e < 64; e++) {
        float we = wrow[e];
        float4 v = enc4[e * 256 + tid];
        acc.x += we * v.x; acc.y += we * v.y; acc.z += we * v.z; acc.w += we * v.w;
    }
    float* o = out + b * 1024 + tid * 4;
    atomicAdd(o + 0, acc.x); atomicAdd(o + 1, acc.y);
    atomicAdd(o + 2, acc.z); atomicAdd(o + 3, acc.w);
}

// ----------------------------------------------------------------
extern "C" void kernel_launch(void* const* d_in, const int* in_sizes, int n_in,
                              void* d_out, int out_size, void* d_ws, size_t ws_size,
                              hipStream_t stream) {
    (void)in_sizes; (void)n_in; (void)out_size; (void)ws_size;
    const float* enc   = (const float*)d_in[0];   // [64,1024,1024]
    const float* dec   = (const float*)d_in[1];   // [64,1,1024]
    const float* Wa_w  = (const float*)d_in[2];   // [1024,1024]
    const float* Wa_b  = (const float*)d_in[3];   // [1024]
    const float* Ua_w  = (const float*)d_in[4];   // [1024,1024]
    const float* Ua_b  = (const float*)d_in[5];   // [1024]
    const float* Va_w  = (const float*)d_in[6];   // [1,1024]
    // d_in[7] = Va_b: softmax-invariant constant shift -> dropped.
    float* out = (float*)d_out;                   // [64,1,1024]

    char* w = (char*)d_ws;
    __bf16* encB = (__bf16*)w;  w += (size_t)MM * 1024 * 2;       // 134 MB
    __bf16* uawB = (__bf16*)w;  w += (size_t)HH * 1024 * 2;       // 2 MB
    float* WaBuf = (float*)w;   w += (size_t)B_ * HH * 4;         // 256 KB
    float* scores = (float*)w;  w += (size_t)MM * 4;              // 256 KB

    zero_kernel<<<dim3(256), 256, 0, stream>>>(scores, out, MM);
    cvt_kernel<<<dim3(2048), 256, 0, stream>>>(enc, encB, (long)MM * 1024 / 4);
    cvt_kernel<<<dim3(256), 256, 0, stream>>>(Ua_w, uawB, (long)HH * 1024 / 4);
    wa_kernel<<<dim3(B_, 16), 256, 0, stream>>>(dec, Wa_w, Wa_b, WaBuf);
    score_gemm<<<dim3(MM / MT, HH / NT), 256, 0, stream>>>(encB, uawB, WaBuf, Ua_b, Va_w, scores);
    softmax_kernel<<<dim3(B_), 256, 0, stream>>>(scores);
    context_kernel<<<dim3(B_, 16), 256, 0, stream>>>(enc, scores, out);
}

// Round 2
// 607.109 us; speedup vs baseline: 1.0828x; 1.0828x over previous
//
#include <hip/hip_runtime.h>
#include <hip/hip_bf16.h>

// Problem dims (fixed): B=64, Te=1024, De=Dd=H=1024.
#define B_  64
#define TE  1024
#define K_  1024
#define HH  1024
#define MM  (B_ * TE)

typedef __bf16 bf16x8 __attribute__((ext_vector_type(8)));
typedef __bf16 bf16x4 __attribute__((ext_vector_type(4)));
typedef float  f32x4  __attribute__((ext_vector_type(4)));

__device__ __forceinline__ float fast_tanh(float x) {
    // tanh(x) = sign(x) * (1 - e^{-2|x|}) / (1 + e^{-2|x|}); branch-free, no overflow.
    float ax = __builtin_fabsf(x);
    float t  = __expf(-2.0f * ax);                 // v_exp_f32 path
    float r  = (1.0f - t) * __builtin_amdgcn_rcpf(1.0f + t);
    return __builtin_copysignf(r, x);
}

// ---------------------------------------------------------------- zero
__global__ void zero_kernel(float* __restrict__ a, float* __restrict__ b, int n) {
    int i = blockIdx.x * blockDim.x + threadIdx.x;
    if (i < n) { a[i] = 0.0f; b[i] = 0.0f; }
}

// ---------------------------------------------------------------- fp32 -> bf16
__global__ void cvt_kernel(const float* __restrict__ in, __bf16* __restrict__ out, long n4) {
    long i = (long)blockIdx.x * blockDim.x + threadIdx.x;
    long stride = (long)gridDim.x * blockDim.x;
    const float4* in4 = (const float4*)in;
    bf16x4* out4 = (bf16x4*)out;
    for (long j = i; j < n4; j += stride) {
        float4 v = in4[j];
        bf16x4 o;
        o[0] = (__bf16)v.x; o[1] = (__bf16)v.y; o[2] = (__bf16)v.z; o[3] = (__bf16)v.w;
        out4[j] = o;
    }
}

// ---------------------------------------------------------------- Wa[b,h] = dec[b]·Wa_w[h] + Wa_b[h]
__global__ void wa_kernel(const float* __restrict__ dec, const float* __restrict__ Wa_w,
                          const float* __restrict__ Wa_b, float* __restrict__ WaOut) {
    int b = blockIdx.x, ht = blockIdx.y;
    int wave = threadIdx.x >> 6, lane = threadIdx.x & 63;
    const float* db = dec + b * 1024;
    for (int i = 0; i < 16; i++) {
        int h = ht * 64 + wave * 16 + i;
        const float* wr = Wa_w + (long)h * 1024;
        float a = 0.0f;
        #pragma unroll
        for (int k = 0; k < 16; k++)
            a += db[lane + 64 * k] * wr[lane + 64 * k];
        #pragma unroll
        for (int off = 32; off > 0; off >>= 1)
            a += __shfl_xor(a, off, 64);
        if (lane == 0) WaOut[b * 1024 + h] = a + Wa_b[h];
    }
}

// ---------------------------------------------------------------- fused score GEMM
// scores[m] += sum_h Va_w[h]*tanh(enc[m,:]·Ua_w[h,:] + Wa[b,h] + Ua_b[h])
// 128-row strip x 512 cols per block (4 n-tiles of 128), BK=64, XOR-swizzled LDS.
#define MT 128
#define KT 64
#define NTILES 4

__global__ __launch_bounds__(256, 4) void score_gemm(
    const __bf16* __restrict__ A,    // [MM][1024] enc bf16
    const __bf16* __restrict__ Bm,   // [1024][1024] Ua_w bf16
    const float* __restrict__ Wa,    // [64][1024]
    const float* __restrict__ Ua_b,  // [1024]
    const float* __restrict__ Va_w,  // [1024]
    float* __restrict__ scores)      // [MM], pre-zeroed, atomic accumulate
{
    __shared__ __bf16 sA[MT * KT];   // 16 KB, swizzled: row r, lds slot s' holds seg s'^(r&7)
    __shared__ __bf16 sB[MT * KT];   // 16 KB
    __shared__ float sVa[512];
    __shared__ float sWU[512];

    const int tid  = threadIdx.x;
    const int wave = tid >> 6;
    const int lane = tid & 63;
    const int quad = lane >> 4;
    const int l16  = lane & 15;
    const int wm   = wave >> 1;
    const int wn   = wave & 1;

    const int rowBase = blockIdx.x * MT;
    const int colBase = blockIdx.y * (NTILES * 128);
    const int b       = rowBase >> 10;

    for (int i = tid; i < 512; i += 256) {
        int h = colBase + i;
        sVa[i] = Va_w[h];
        sWU[i] = Wa[b * 1024 + h] + Ua_b[h];
    }
    // (first __syncthreads inside k-loop orders these vs epilogue reads)

    float rs[4][4] = {};             // [s][reg] partial scores, accumulated over nt & t

    const long aBase = (long)rowBase * K_;
    for (int nt = 0; nt < NTILES; nt++) {
        f32x4 acc[4][4] = {};
        const long bBase = (long)(colBase + nt * 128) * K_;

        for (int k0 = 0; k0 < K_; k0 += KT) {
            __syncthreads();         // prior ds_reads done before overwrite
            #pragma unroll
            for (int i = 0; i < 4; i++) {
                int c = i * 256 + tid;          // 16B chunk; lds addr = c*16 (wave-uniform + lane*16)
                int r = c >> 3, slot = c & 7;
                int seg = slot ^ (r & 7);       // swizzle: slot holds global seg
                __builtin_amdgcn_global_load_lds(
                    (const __attribute__((address_space(1))) unsigned int*)(A + aBase + (long)r * K_ + k0 + seg * 8),
                    (__attribute__((address_space(3))) unsigned int*)(sA + c * 8), 16, 0, 0);
            }
            #pragma unroll
            for (int i = 0; i < 4; i++) {
                int c = i * 256 + tid;
                int r = c >> 3, slot = c & 7;
                int seg = slot ^ (r & 7);
                __builtin_amdgcn_global_load_lds(
                    (const __attribute__((address_space(1))) unsigned int*)(Bm + bBase + (long)r * K_ + k0 + seg * 8),
                    (__attribute__((address_space(3))) unsigned int*)(sB + c * 8), 16, 0, 0);
            }
            __syncthreads();         // staged data visible

            #pragma unroll
            for (int ks = 0; ks < 2; ks++) {
                bf16x8 bfr[4];
                #pragma unroll
                for (int t = 0; t < 4; t++) {
                    int r = wn * 64 + t * 16 + l16;
                    int slot = (ks * 4 + quad) ^ (r & 7);
                    bfr[t] = *(const bf16x8*)(sB + r * KT + slot * 8);
                }
                #pragma unroll
                for (int s = 0; s < 4; s++) {
                    int r = wm * 64 + s * 16 + l16;
                    int slot = (ks * 4 + quad) ^ (r & 7);
                    bf16x8 af = *(const bf16x8*)(sA + r * KT + slot * 8);
                    #pragma unroll
                    for (int t = 0; t < 4; t++)
                        acc[s][t] = __builtin_amdgcn_mfma_f32_16x16x32_bf16(af, bfr[t], acc[s][t], 0, 0, 0);
                }
            }
        }

        // per-nt epilogue: fold this 128-col panel into rs. C/D: row=quad*4+reg, col=l16.
        #pragma unroll
        for (int s = 0; s < 4; s++)
            #pragma unroll
            for (int t = 0; t < 4; t++) {
                int hl = nt * 128 + wn * 64 + t * 16 + l16;
                float va = sVa[hl], wu = sWU[hl];
                #pragma unroll
                for (int r = 0; r < 4; r++)
                    rs[s][r] += va * fast_tanh(acc[s][t][r] + wu);
            }
    }

    // one reduce at the end: sum across the 16 columns held by l16 lanes
    #pragma unroll
    for (int s = 0; s < 4; s++)
        #pragma unroll
        for (int r = 0; r < 4; r++) {
            float v = rs[s][r];
            v += __shfl_xor(v, 1, 64);
            v += __shfl_xor(v, 2, 64);
            v += __shfl_xor(v, 4, 64);
            v += __shfl_xor(v, 8, 64);
            if (l16 == 0)
                atomicAdd(&scores[rowBase + wm * 64 + s * 16 + quad * 4 + r], v);
        }
}

// ---------------------------------------------------------------- softmax over Te, in place
__global__ void softmax_kernel(float* __restrict__ s) {
    __shared__ float red[256];
    int b = blockIdx.x, tid = threadIdx.x;
    float4* row = (float4*)(s + b * 1024);
    float4 v = row[tid];
    float m = fmaxf(fmaxf(v.x, v.y), fmaxf(v.z, v.w));
    red[tid] = m; __syncthreads();
    for (int off = 128; off > 0; off >>= 1) {
        if (tid < off) red[tid] = fmaxf(red[tid], red[tid + off]);
        __syncthreads();
    }
    m = red[0]; __syncthreads();
    v.x = expf(v.x - m); v.y = expf(v.y - m); v.z = expf(v.z - m); v.w = expf(v.w - m);
    red[tid] = v.x + v.y + v.z + v.w; __syncthreads();
    for (int off = 128; off > 0; off >>= 1) {
        if (tid < off) red[tid] += red[tid + off];
        __syncthreads();
    }
    float inv = 1.0f / red[0];
    v.x *= inv; v.y *= inv; v.z *= inv; v.w *= inv;
    row[tid] = v;
}

// ---------------------------------------------------------------- context from bf16 enc
__global__ void context_kernel(const __bf16* __restrict__ enc, const float* __restrict__ w,
                               float* __restrict__ out) {
    int b = blockIdx.x, ec = blockIdx.y, tid = threadIdx.x;
    const bf16x4* enc4 = (const bf16x4*)(enc + ((long)b * 1024 + ec * 64) * 1024);
    const float* wrow = w + b * 1024 + ec * 64;
    float ax = 0, ay = 0, az = 0, aw = 0;
    for (int e = 0; e < 64; e++) {
        float we = wrow[e];
        bf16x4 v = enc4[e * 256 + tid];
        ax += we * (float)v[0]; ay += we * (float)v[1];
        az += we * (float)v[2]; aw += we * (float)v[3];
    }
    float* o = out + b * 1024 + tid * 4;
    atomicAdd(o + 0, ax); atomicAdd(o + 1, ay);
    atomicAdd(o + 2, az); atomicAdd(o + 3, aw);
}

// ----------------------------------------------------------------
extern "C" void kernel_launch(void* const* d_in, const int* in_sizes, int n_in,
                              void* d_out, int out_size, void* d_ws, size_t ws_size,
                              hipStream_t stream) {
    (void)in_sizes; (void)n_in; (void)out_size; (void)ws_size;
    const float* enc   = (const float*)d_in[0];
    const float* dec   = (const float*)d_in[1];
    const float* Wa_w  = (const float*)d_in[2];
    const float* Wa_b  = (const float*)d_in[3];
    const float* Ua_w  = (const float*)d_in[4];
    const float* Ua_b  = (const float*)d_in[5];
    const float* Va_w  = (const float*)d_in[6];
    // d_in[7] = Va_b: softmax-invariant -> dropped.
    float* out = (float*)d_out;

    char* w = (char*)d_ws;
    __bf16* encB = (__bf16*)w;  w += (size_t)MM * 1024 * 2;
    __bf16* uawB = (__bf16*)w;  w += (size_t)HH * 1024 * 2;
    float* WaBuf = (float*)w;   w += (size_t)B_ * HH * 4;
    float* scores = (float*)w;  w += (size_t)MM * 4;

    zero_kernel<<<dim3(256), 256, 0, stream>>>(scores, out, MM);
    cvt_kernel<<<dim3(4096), 256, 0, stream>>>(enc, encB, (long)MM * 1024 / 4);
    cvt_kernel<<<dim3(256), 256, 0, stream>>>(Ua_w, uawB, (long)HH * 1024 / 4);
    wa_kernel<<<dim3(B_, 16), 256, 0, stream>>>(dec, Wa_w, Wa_b, WaBuf);
    score_gemm<<<dim3(MM / MT, HH / (NTILES * 128)), 256, 0, stream>>>(encB, uawB, WaBuf, Ua_b, Va_w, scores);
    softmax_kernel<<<dim3(B_), 256, 0, stream>>>(scores);
    context_kernel<<<dim3(B_, 16), 256, 0, stream>>>(encB, scores, out);
}

// Round 3
// 587.932 us; speedup vs baseline: 1.1181x; 1.0326x over previous
//
#include <hip/hip_runtime.h>
#include <hip/hip_bf16.h>

// Problem dims (fixed): B=64, Te=1024, De=Dd=H=1024.
#define B_  64
#define TE  1024
#define K_  1024
#define HH  1024
#define MM  (B_ * TE)

typedef __bf16 bf16x8 __attribute__((ext_vector_type(8)));
typedef __bf16 bf16x4 __attribute__((ext_vector_type(4)));
typedef float  f32x4  __attribute__((ext_vector_type(4)));

__device__ __forceinline__ float fast_tanh(float x) {
    // tanh(x) = sign(x) * (1 - e^{-2|x|}) / (1 + e^{-2|x|}); branch-free, no overflow.
    float ax = __builtin_fabsf(x);
    float t  = __expf(-2.0f * ax);
    float r  = (1.0f - t) * __builtin_amdgcn_rcpf(1.0f + t);
    return __builtin_copysignf(r, x);
}

// ---------------------------------------------------------------- fp32 -> bf16
__global__ void cvt_kernel(const float* __restrict__ in, __bf16* __restrict__ out, long n4) {
    long i = (long)blockIdx.x * blockDim.x + threadIdx.x;
    long stride = (long)gridDim.x * blockDim.x;
    const float4* in4 = (const float4*)in;
    bf16x4* out4 = (bf16x4*)out;
    for (long j = i; j < n4; j += stride) {
        float4 v = in4[j];
        bf16x4 o;
        o[0] = (__bf16)v.x; o[1] = (__bf16)v.y; o[2] = (__bf16)v.z; o[3] = (__bf16)v.w;
        out4[j] = o;
    }
}

// ---------------------------------------------------------------- Wa[b,h] = dec[b]·Wa_w[h] + Wa_b[h]
__global__ void wa_kernel(const float* __restrict__ dec, const float* __restrict__ Wa_w,
                          const float* __restrict__ Wa_b, float* __restrict__ WaOut) {
    int b = blockIdx.x, ht = blockIdx.y;
    int wave = threadIdx.x >> 6, lane = threadIdx.x & 63;
    const float* db = dec + b * 1024;
    for (int i = 0; i < 16; i++) {
        int h = ht * 64 + wave * 16 + i;
        const float* wr = Wa_w + (long)h * 1024;
        float a = 0.0f;
        #pragma unroll
        for (int k = 0; k < 16; k++)
            a += db[lane + 64 * k] * wr[lane + 64 * k];
        #pragma unroll
        for (int off = 32; off > 0; off >>= 1)
            a += __shfl_xor(a, off, 64);
        if (lane == 0) WaOut[b * 1024 + h] = a + Wa_b[h];
    }
}

// ---------------------------------------------------------------- fused score GEMM
// scores[m] += sum_h Va_w[h]*tanh(enc[m,:]·Ua_w[h,:] + Wa[b,h] + Ua_b[h])
// Block: 128 rows x 256 cols, single K pass. 4 waves in 2x2; wave tile 64x128
// (acc = 4x8 subtiles of 16x16 = 128 f32/lane). KT=64, XOR-swizzled LDS.
// Grid swizzle: 4 y-blocks of the same x-strip land on one XCD (bid%8) so the
// A strip is HBM-fetched once, L2-served 3x.
#define MT 128
#define NP 256
#define KT 64

__global__ __launch_bounds__(256, 2) void score_gemm(
    const __bf16* __restrict__ A,    // [MM][1024] enc bf16
    const __bf16* __restrict__ Bm,   // [1024][1024] Ua_w bf16
    const float* __restrict__ Wa,    // [64][1024]
    const float* __restrict__ Ua_b,  // [1024]
    const float* __restrict__ Va_w,  // [1024]
    float* __restrict__ scores)      // [MM], pre-zeroed, atomic accumulate
{
    __shared__ __bf16 sA[MT * KT];   // 16 KB, swizzled: row r, slot s' holds seg s'^(r&7)
    __shared__ __bf16 sB[NP * KT];   // 32 KB
    __shared__ float sVa[NP];
    __shared__ float sWU[NP];

    const int tid  = threadIdx.x;
    const int wave = tid >> 6;
    const int lane = tid & 63;
    const int quad = lane >> 4;
    const int l16  = lane & 15;
    const int wm   = wave >> 1;      // 0..1 -> 64-row half
    const int wn   = wave & 1;       // 0..1 -> 128-col half

    // bid -> (x strip, y quarter); groups of 32 bids = 8 XCD slots x 4 y sharing x.
    const int bid = blockIdx.x;
    const int grp = bid >> 5;
    const int r5  = bid & 31;
    const int y   = r5 >> 3;
    const int x   = grp * 8 + (r5 & 7);

    const int rowBase = x * MT;
    const int colBase = y * NP;
    const int b       = rowBase >> 10;

    if (tid < NP) {
        int h = colBase + tid;
        sVa[tid] = Va_w[h];
        sWU[tid] = Wa[b * 1024 + h] + Ua_b[h];
    }

    f32x4 acc[4][8] = {};            // [m-subtile s][n-subtile t]

    const long aBase = (long)rowBase * K_;
    const long bBase = (long)colBase * K_;

    for (int k0 = 0; k0 < K_; k0 += KT) {
        __syncthreads();             // prior ds_reads done before overwrite
        #pragma unroll
        for (int i = 0; i < 4; i++) {            // A: 128x64 = 1024 chunks
            int c = i * 256 + tid;
            int r = c >> 3, slot = c & 7;
            int seg = slot ^ (r & 7);
            __builtin_amdgcn_global_load_lds(
                (const __attribute__((address_space(1))) unsigned int*)(A + aBase + (long)r * K_ + k0 + seg * 8),
                (__attribute__((address_space(3))) unsigned int*)(sA + c * 8), 16, 0, 0);
        }
        #pragma unroll
        for (int i = 0; i < 8; i++) {            // B: 256x64 = 2048 chunks
            int c = i * 256 + tid;
            int r = c >> 3, slot = c & 7;
            int seg = slot ^ (r & 7);
            __builtin_amdgcn_global_load_lds(
                (const __attribute__((address_space(1))) unsigned int*)(Bm + bBase + (long)r * K_ + k0 + seg * 8),
                (__attribute__((address_space(3))) unsigned int*)(sB + c * 8), 16, 0, 0);
        }
        __syncthreads();             // staged data visible

        #pragma unroll
        for (int ks = 0; ks < 2; ks++) {
            bf16x8 bfr[8];
            #pragma unroll
            for (int t = 0; t < 8; t++) {
                int r = wn * 128 + t * 16 + l16;
                int slot = (ks * 4 + quad) ^ (r & 7);
                bfr[t] = *(const bf16x8*)(sB + r * KT + slot * 8);
            }
            #pragma unroll
            for (int s = 0; s < 4; s++) {
                int r = wm * 64 + s * 16 + l16;
                int slot = (ks * 4 + quad) ^ (r & 7);
                bf16x8 af = *(const bf16x8*)(sA + r * KT + slot * 8);
                #pragma unroll
                for (int t = 0; t < 8; t++)
                    acc[s][t] = __builtin_amdgcn_mfma_f32_16x16x32_bf16(af, bfr[t], acc[s][t], 0, 0, 0);
            }
        }
    }

    // Epilogue. C/D layout: row = quad*4 + reg, col = l16.
    float rs[4][4] = {};
    #pragma unroll
    for (int s = 0; s < 4; s++)
        #pragma unroll
        for (int t = 0; t < 8; t++) {
            int hl = wn * 128 + t * 16 + l16;
            float va = sVa[hl], wu = sWU[hl];
            #pragma unroll
            for (int r = 0; r < 4; r++)
                rs[s][r] += va * fast_tanh(acc[s][t][r] + wu);
        }

    #pragma unroll
    for (int s = 0; s < 4; s++)
        #pragma unroll
        for (int r = 0; r < 4; r++) {
            float v = rs[s][r];
            v += __shfl_xor(v, 1, 64);
            v += __shfl_xor(v, 2, 64);
            v += __shfl_xor(v, 4, 64);
            v += __shfl_xor(v, 8, 64);
            if (l16 == 0)
                atomicAdd(&scores[rowBase + wm * 64 + s * 16 + quad * 4 + r], v);
        }
}

// ---------------------------------------------------------------- softmax over Te, in place
__global__ void softmax_kernel(float* __restrict__ s) {
    __shared__ float red[256];
    int b = blockIdx.x, tid = threadIdx.x;
    float4* row = (float4*)(s + b * 1024);
    float4 v = row[tid];
    float m = fmaxf(fmaxf(v.x, v.y), fmaxf(v.z, v.w));
    red[tid] = m; __syncthreads();
    for (int off = 128; off > 0; off >>= 1) {
        if (tid < off) red[tid] = fmaxf(red[tid], red[tid + off]);
        __syncthreads();
    }
    m = red[0]; __syncthreads();
    v.x = expf(v.x - m); v.y = expf(v.y - m); v.z = expf(v.z - m); v.w = expf(v.w - m);
    red[tid] = v.x + v.y + v.z + v.w; __syncthreads();
    for (int off = 128; off > 0; off >>= 1) {
        if (tid < off) red[tid] += red[tid + off];
        __syncthreads();
    }
    float inv = 1.0f / red[0];
    v.x *= inv; v.y *= inv; v.z *= inv; v.w *= inv;
    row[tid] = v;
}

// ---------------------------------------------------------------- context from bf16 enc
__global__ void context_kernel(const __bf16* __restrict__ enc, const float* __restrict__ w,
                               float* __restrict__ out) {
    int b = blockIdx.x, ec = blockIdx.y, tid = threadIdx.x;
    const bf16x4* enc4 = (const bf16x4*)(enc + ((long)b * 1024 + ec * 64) * 1024);
    const float* wrow = w + b * 1024 + ec * 64;
    float ax = 0, ay = 0, az = 0, aw = 0;
    for (int e = 0; e < 64; e++) {
        float we = wrow[e];
        bf16x4 v = enc4[e * 256 + tid];
        ax += we * (float)v[0]; ay += we * (float)v[1];
        az += we * (float)v[2]; aw += we * (float)v[3];
    }
    float* o = out + b * 1024 + tid * 4;
    atomicAdd(o + 0, ax); atomicAdd(o + 1, ay);
    atomicAdd(o + 2, az); atomicAdd(o + 3, aw);
}

// ----------------------------------------------------------------
extern "C" void kernel_launch(void* const* d_in, const int* in_sizes, int n_in,
                              void* d_out, int out_size, void* d_ws, size_t ws_size,
                              hipStream_t stream) {
    (void)in_sizes; (void)n_in; (void)ws_size;
    const float* enc   = (const float*)d_in[0];
    const float* dec   = (const float*)d_in[1];
    const float* Wa_w  = (const float*)d_in[2];
    const float* Wa_b  = (const float*)d_in[3];
    const float* Ua_w  = (const float*)d_in[4];
    const float* Ua_b  = (const float*)d_in[5];
    const float* Va_w  = (const float*)d_in[6];
    // d_in[7] = Va_b: softmax-invariant -> dropped.
    float* out = (float*)d_out;

    char* w = (char*)d_ws;
    __bf16* encB = (__bf16*)w;  w += (size_t)MM * 1024 * 2;
    __bf16* uawB = (__bf16*)w;  w += (size_t)HH * 1024 * 2;
    float* WaBuf = (float*)w;   w += (size_t)B_ * HH * 4;
    float* scores = (float*)w;  w += (size_t)MM * 4;

    hipMemsetAsync(scores, 0, (size_t)MM * 4, stream);
    hipMemsetAsync(out, 0, (size_t)out_size * 4, stream);
    cvt_kernel<<<dim3(4096), 256, 0, stream>>>(enc, encB, (long)MM * 1024 / 4);
    cvt_kernel<<<dim3(256), 256, 0, stream>>>(Ua_w, uawB, (long)HH * 1024 / 4);
    wa_kernel<<<dim3(B_, 16), 256, 0, stream>>>(dec, Wa_w, Wa_b, WaBuf);
    score_gemm<<<dim3((MM / MT) * (HH / NP)), 256, 0, stream>>>(encB, uawB, WaBuf, Ua_b, Va_w, scores);
    softmax_kernel<<<dim3(B_), 256, 0, stream>>>(scores);
    context_kernel<<<dim3(B_, 16), 256, 0, stream>>>(encB, scores, out);
}

// Round 4
// 528.212 us; speedup vs baseline: 1.2445x; 1.1131x over previous
//
#include <hip/hip_runtime.h>
#include <hip/hip_bf16.h>

// Problem dims (fixed): B=64, Te=1024, De=Dd=H=1024.
#define B_  64
#define TE  1024
#define K_  1024
#define HH  1024
#define MM  (B_ * TE)

typedef __bf16 bf16x8 __attribute__((ext_vector_type(8)));
typedef __bf16 bf16x4 __attribute__((ext_vector_type(4)));
typedef float  f32x4  __attribute__((ext_vector_type(4)));

__device__ __forceinline__ float fast_tanh(float x) {
    // tanh(x) = sign(x) * (1 - e^{-2|x|}) / (1 + e^{-2|x|}); branch-free, no overflow.
    float ax = __builtin_fabsf(x);
    float t  = __expf(-2.0f * ax);
    float r  = (1.0f - t) * __builtin_amdgcn_rcpf(1.0f + t);
    return __builtin_copysignf(r, x);
}

// ---------------------------------------------------------------- fp32 -> bf16 (small: Ua_w only)
__global__ void cvt_kernel(const float* __restrict__ in, __bf16* __restrict__ out, long n4) {
    long i = (long)blockIdx.x * blockDim.x + threadIdx.x;
    long stride = (long)gridDim.x * blockDim.x;
    const float4* in4 = (const float4*)in;
    bf16x4* out4 = (bf16x4*)out;
    for (long j = i; j < n4; j += stride) {
        float4 v = in4[j];
        bf16x4 o;
        o[0] = (__bf16)v.x; o[1] = (__bf16)v.y; o[2] = (__bf16)v.z; o[3] = (__bf16)v.w;
        out4[j] = o;
    }
}

// ---------------------------------------------------------------- Wa[b,h] = dec[b]·Wa_w[h] + Wa_b[h]
__global__ void wa_kernel(const float* __restrict__ dec, const float* __restrict__ Wa_w,
                          const float* __restrict__ Wa_b, float* __restrict__ WaOut) {
    int b = blockIdx.x, ht = blockIdx.y;
    int wave = threadIdx.x >> 6, lane = threadIdx.x & 63;
    const float* db = dec + b * 1024;
    for (int i = 0; i < 16; i++) {
        int h = ht * 64 + wave * 16 + i;
        const float* wr = Wa_w + (long)h * 1024;
        float a = 0.0f;
        #pragma unroll
        for (int k = 0; k < 16; k++)
            a += db[lane + 64 * k] * wr[lane + 64 * k];
        #pragma unroll
        for (int off = 32; off > 0; off >>= 1)
            a += __shfl_xor(a, off, 64);
        if (lane == 0) WaOut[b * 1024 + h] = a + Wa_b[h];
    }
}

// ---------------------------------------------------------------- fused score GEMM
// scores[m] += sum_h Va_w[h]*tanh(enc[m,:]·Ua_w[h,:] + Wa[b,h] + Ua_b[h])
// A staged directly from fp32 enc: reg prefetch -> packed cvt -> ds_write.
// y==0 blocks also emit the bf16 A tile to encB (consumed later by context).
// Block: 128 rows x 256 cols, single K pass; wave tile 64x128; KT=64; XOR swizzle.
#define MT 128
#define NP 256
#define KT 64

__global__ __launch_bounds__(256, 2) void score_gemm(
    const float* __restrict__ Af,    // [MM][1024] enc fp32
    __bf16* __restrict__ encB,       // [MM][1024] bf16 out (written by y==0 blocks)
    const __bf16* __restrict__ Bm,   // [1024][1024] Ua_w bf16
    const float* __restrict__ Wa,    // [64][1024]
    const float* __restrict__ Ua_b,  // [1024]
    const float* __restrict__ Va_w,  // [1024]
    float* __restrict__ scores)      // [MM], pre-zeroed, atomic accumulate
{
    __shared__ __bf16 sA[MT * KT];   // 16 KB, swizzled: row r, slot s' holds seg s'^(r&7)
    __shared__ __bf16 sB[NP * KT];   // 32 KB
    __shared__ float sVa[NP];
    __shared__ float sWU[NP];

    const int tid  = threadIdx.x;
    const int wave = tid >> 6;
    const int lane = tid & 63;
    const int quad = lane >> 4;
    const int l16  = lane & 15;
    const int wm   = wave >> 1;      // 0..1 -> 64-row half
    const int wn   = wave & 1;       // 0..1 -> 128-col half

    // bid -> (x strip, y quarter); groups of 32 bids = 8 XCD slots x 4 y sharing x.
    const int bid = blockIdx.x;
    const int grp = bid >> 5;
    const int r5  = bid & 31;
    const int y   = r5 >> 3;
    const int x   = grp * 8 + (r5 & 7);

    const int rowBase = x * MT;
    const int colBase = y * NP;
    const int b       = rowBase >> 10;
    const bool wb     = (y == 0);    // this block writes the bf16 A strip

    if (tid < NP) {
        int h = colBase + tid;
        sVa[tid] = Va_w[h];
        sWU[tid] = Wa[b * 1024 + h] + Ua_b[h];
    }

    // My 4 A chunks (8 bf16 each): c = i*256+tid; r=c>>3; seg=(c&7)^(r&7)
    int rr[4], sg[4];
    #pragma unroll
    for (int i = 0; i < 4; i++) {
        int c = i * 256 + tid;
        rr[i] = c >> 3;
        sg[i] = (c & 7) ^ (rr[i] & 7);
    }

    f32x4 acc[4][8] = {};            // [m-subtile s][n-subtile t]

    const long aBase = (long)rowBase * K_;
    const long bBase = (long)colBase * K_;

    float4 pre[4][2];
    #pragma unroll
    for (int i = 0; i < 4; i++) {    // prefetch A(k0=0)
        const float4* p = (const float4*)(Af + aBase + (long)rr[i] * K_ + sg[i] * 8);
        pre[i][0] = p[0]; pre[i][1] = p[1];
    }

    for (int k0 = 0; k0 < K_; k0 += KT) {
        __syncthreads();             // prior ds_reads done; prefetch loads drained here
        #pragma unroll
        for (int i = 0; i < 4; i++) {            // A: cvt + ds_write (+ optional writeback)
            bf16x8 v;
            v[0] = (__bf16)pre[i][0].x; v[1] = (__bf16)pre[i][0].y;
            v[2] = (__bf16)pre[i][0].z; v[3] = (__bf16)pre[i][0].w;
            v[4] = (__bf16)pre[i][1].x; v[5] = (__bf16)pre[i][1].y;
            v[6] = (__bf16)pre[i][1].z; v[7] = (__bf16)pre[i][1].w;
            *(bf16x8*)(sA + (i * 256 + tid) * 8) = v;
            if (wb)
                *(bf16x8*)(encB + aBase + (long)rr[i] * K_ + k0 + sg[i] * 8) = v;
        }
        #pragma unroll
        for (int i = 0; i < 8; i++) {            // B: 256x64 = 2048 chunks via async LDS
            int c = i * 256 + tid;
            int r = c >> 3, slot = c & 7;
            int seg = slot ^ (r & 7);
            __builtin_amdgcn_global_load_lds(
                (const __attribute__((address_space(1))) unsigned int*)(Bm + bBase + (long)r * K_ + k0 + seg * 8),
                (__attribute__((address_space(3))) unsigned int*)(sB + c * 8), 16, 0, 0);
        }
        __syncthreads();             // staged data visible

        if (k0 + KT < K_) {          // issue next A prefetch; hides under MFMA phase
            #pragma unroll
            for (int i = 0; i < 4; i++) {
                const float4* p = (const float4*)(Af + aBase + (long)rr[i] * K_ + (k0 + KT) + sg[i] * 8);
                pre[i][0] = p[0]; pre[i][1] = p[1];
            }
        }

        #pragma unroll
        for (int ks = 0; ks < 2; ks++) {
            bf16x8 bfr[8];
            #pragma unroll
            for (int t = 0; t < 8; t++) {
                int r = wn * 128 + t * 16 + l16;
                int slot = (ks * 4 + quad) ^ (r & 7);
                bfr[t] = *(const bf16x8*)(sB + r * KT + slot * 8);
            }
            #pragma unroll
            for (int s = 0; s < 4; s++) {
                int r = wm * 64 + s * 16 + l16;
                int slot = (ks * 4 + quad) ^ (r & 7);
                bf16x8 af = *(const bf16x8*)(sA + r * KT + slot * 8);
                #pragma unroll
                for (int t = 0; t < 8; t++)
                    acc[s][t] = __builtin_amdgcn_mfma_f32_16x16x32_bf16(af, bfr[t], acc[s][t], 0, 0, 0);
            }
        }
    }

    // Epilogue. C/D layout: row = quad*4 + reg, col = l16.
    float rs[4][4] = {};
    #pragma unroll
    for (int s = 0; s < 4; s++)
        #pragma unroll
        for (int t = 0; t < 8; t++) {
            int hl = wn * 128 + t * 16 + l16;
            float va = sVa[hl], wu = sWU[hl];
            #pragma unroll
            for (int r = 0; r < 4; r++)
                rs[s][r] += va * fast_tanh(acc[s][t][r] + wu);
        }

    #pragma unroll
    for (int s = 0; s < 4; s++)
        #pragma unroll
        for (int r = 0; r < 4; r++) {
            float v = rs[s][r];
            v += __shfl_xor(v, 1, 64);
            v += __shfl_xor(v, 2, 64);
            v += __shfl_xor(v, 4, 64);
            v += __shfl_xor(v, 8, 64);
            if (l16 == 0)
                atomicAdd(&scores[rowBase + wm * 64 + s * 16 + quad * 4 + r], v);
        }
}

// ---------------------------------------------------------------- softmax over Te, in place
__global__ void softmax_kernel(float* __restrict__ s) {
    __shared__ float red[256];
    int b = blockIdx.x, tid = threadIdx.x;
    float4* row = (float4*)(s + b * 1024);
    float4 v = row[tid];
    float m = fmaxf(fmaxf(v.x, v.y), fmaxf(v.z, v.w));
    red[tid] = m; __syncthreads();
    for (int off = 128; off > 0; off >>= 1) {
        if (tid < off) red[tid] = fmaxf(red[tid], red[tid + off]);
        __syncthreads();
    }
    m = red[0]; __syncthreads();
    v.x = expf(v.x - m); v.y = expf(v.y - m); v.z = expf(v.z - m); v.w = expf(v.w - m);
    red[tid] = v.x + v.y + v.z + v.w; __syncthreads();
    for (int off = 128; off > 0; off >>= 1) {
        if (tid < off) red[tid] += red[tid + off];
        __syncthreads();
    }
    float inv = 1.0f / red[0];
    v.x *= inv; v.y *= inv; v.z *= inv; v.w *= inv;
    row[tid] = v;
}

// ---------------------------------------------------------------- context from bf16 enc
__global__ void context_kernel(const __bf16* __restrict__ enc, const float* __restrict__ w,
                               float* __restrict__ out) {
    int b = blockIdx.x, ec = blockIdx.y, tid = threadIdx.x;
    const bf16x4* enc4 = (const bf16x4*)(enc + ((long)b * 1024 + ec * 64) * 1024);
    const float* wrow = w + b * 1024 + ec * 64;
    float ax = 0, ay = 0, az = 0, aw = 0;
    for (int e = 0; e < 64; e++) {
        float we = wrow[e];
        bf16x4 v = enc4[e * 256 + tid];
        ax += we * (float)v[0]; ay += we * (float)v[1];
        az += we * (float)v[2]; aw += we * (float)v[3];
    }
    float* o = out + b * 1024 + tid * 4;
    atomicAdd(o + 0, ax); atomicAdd(o + 1, ay);
    atomicAdd(o + 2, az); atomicAdd(o + 3, aw);
}

// ----------------------------------------------------------------
extern "C" void kernel_launch(void* const* d_in, const int* in_sizes, int n_in,
                              void* d_out, int out_size, void* d_ws, size_t ws_size,
                              hipStream_t stream) {
    (void)in_sizes; (void)n_in; (void)ws_size;
    const float* enc   = (const float*)d_in[0];
    const float* dec   = (const float*)d_in[1];
    const float* Wa_w  = (const float*)d_in[2];
    const float* Wa_b  = (const float*)d_in[3];
    const float* Ua_w  = (const float*)d_in[4];
    const float* Ua_b  = (const float*)d_in[5];
    const float* Va_w  = (const float*)d_in[6];
    // d_in[7] = Va_b: softmax-invariant -> dropped.
    float* out = (float*)d_out;

    char* w = (char*)d_ws;
    __bf16* encB = (__bf16*)w;  w += (size_t)MM * 1024 * 2;
    __bf16* uawB = (__bf16*)w;  w += (size_t)HH * 1024 * 2;
    float* WaBuf = (float*)w;   w += (size_t)B_ * HH * 4;
    float* scores = (float*)w;  w += (size_t)MM * 4;

    hipMemsetAsync(scores, 0, (size_t)MM * 4, stream);
    hipMemsetAsync(out, 0, (size_t)out_size * 4, stream);
    cvt_kernel<<<dim3(256), 256, 0, stream>>>(Ua_w, uawB, (long)HH * 1024 / 4);
    wa_kernel<<<dim3(B_, 16), 256, 0, stream>>>(dec, Wa_w, Wa_b, WaBuf);
    score_gemm<<<dim3((MM / MT) * (HH / NP)), 256, 0, stream>>>(enc, encB, uawB, WaBuf, Ua_b, Va_w, scores);
    softmax_kernel<<<dim3(B_), 256, 0, stream>>>(scores);
    context_kernel<<<dim3(B_, 16), 256, 0, stream>>>(encB, scores, out);
}